// Round 6
// baseline (461.069 us; speedup 1.0000x reference)
//
#include <hip/hip_runtime.h>
#include <hip/hip_bf16.h>
#include <string.h>

#define BB 4
#define LL 128
#define DM 256
#define VV 50257
#define VPAD 50304   // 786 tiles * 64; also 393 * 128
#define DW 768
#define HH 8
#define EE 32

typedef __attribute__((ext_vector_type(8))) short sh8;    // 8 bf16 = 4 VGPR
typedef __attribute__((ext_vector_type(4))) short sh4;    // 4 bf16 = 2 VGPR
typedef __attribute__((ext_vector_type(4))) float f32x4;  // MFMA accum

static __device__ inline unsigned short bfbits(float x) {
  __hip_bfloat16 h = __float2bfloat16(x);
  unsigned short u;
  __builtin_memcpy(&u, &h, 2);
  return u;
}

// global -> LDS direct 16B copy (per-lane global src, wave-uniform LDS base;
// HW adds lane*16 to the LDS destination)
#define GLDS16(gsrc, ldst)                                                    \
  __builtin_amdgcn_global_load_lds(                                          \
      (const __attribute__((address_space(1))) void*)(gsrc),                 \
      (__attribute__((address_space(3))) void*)(ldst), 16, 0, 0)

#define WAIT_VM(N)                                                           \
  __builtin_amdgcn_sched_barrier(0);                                         \
  asm volatile("s_waitcnt vmcnt(" #N ")" ::: "memory");                      \
  __builtin_amdgcn_sched_barrier(0)
#define WAIT_LGKM0                                                           \
  asm volatile("s_waitcnt lgkmcnt(0)" ::: "memory");                         \
  __builtin_amdgcn_sched_barrier(0)
#define SBARRIER                                                             \
  __builtin_amdgcn_sched_barrier(0);                                         \
  __builtin_amdgcn_s_barrier();                                              \
  __builtin_amdgcn_sched_barrier(0)

// ------------- prep: wtrans (blocks 0..95) + qproj (blocks 96..607) ---------
// wtrans: Wk/Wv fp32 [768][256] -> bf16 [256][768] via 64x64 LDS transpose.
// qproj : Qb = bf16(scale * (tse @ Wq + bq)); scale folds 1/sqrt(32)*log2(e)
// so attn softmax can use exp2 directly.
__global__ __launch_bounds__(256) void prep_kernel(
    const float* __restrict__ Wk, const float* __restrict__ Wv,
    unsigned short* __restrict__ Wkt, unsigned short* __restrict__ Wvt,
    const float* __restrict__ tse, const float* __restrict__ Wq,
    const float* __restrict__ bq, unsigned short* __restrict__ Qb) {
  __shared__ float tileS[64][65];
  int bid = blockIdx.x;
  int t = threadIdx.x;
  if (bid < 96) {
    int z = bid / 48, rem = bid - z * 48;
    int x = rem % 12, y = rem / 12;
    const float* src = z ? Wv : Wk;
    unsigned short* dst = z ? Wvt : Wkt;
    int k0 = x * 64, n0 = y * 64;
    int c = t & 63, rb = t >> 6;
#pragma unroll
    for (int j = 0; j < 16; ++j) {
      int r = j * 4 + rb;
      tileS[r][c] = src[(size_t)(k0 + r) * DM + n0 + c];
    }
    __syncthreads();
#pragma unroll
    for (int j = 0; j < 16; ++j) {
      int r = j * 4 + rb;
      dst[(size_t)(n0 + r) * DW + k0 + c] = bfbits(tileS[c][r]);
    }
  } else {
    int r = bid - 96;  // 0..511
    int n = t;         // 0..255
    float* row = &tileS[0][0];
    row[n] = tse[r * DM + n];
    __syncthreads();
    float acc = bq[n];
#pragma unroll 8
    for (int k = 0; k < DM; ++k)
      acc = fmaf(row[k], Wq[k * DM + n], acc);
    const float scale = 0.17677669529663687f * 1.4426950408889634f;
    Qb[r * DM + n] = bfbits(acc * scale);
  }
}

// ------------- K,V projection via MFMA: [VPAD,768]@[768,256] x2 -------------
// v3 (fixed): occupancy-first. Tile 64 rows x 128 cols (grid 1572), 3 blk/CU:
//  - WE A-frags loaded DIRECTLY global->regs, ISSUED BEFORE the stage loads
//    (vmcnt is FIFO: waiting for A must drain everything older, so A must be
//    OLDER than the in-flight stage, not newer -- else every step drains the
//    pipeline). sched_barrier pins the issue order.
//  - K/V (Wkt/Wvt bf16) triple-buffered via global_load_lds, stage-ahead-2,
//    ONE raw s_barrier + counted vmcnt per K-step (never drains mid-loop).
//    Restage buffer = (kt+2)%3 = (p==0 ? 2 : p-1): consumed at step kt-1;
//    all waves past this step's barrier have passed the compiler's lgkm wait
//    for those ds_reads, so the restage cannot race them.
//  - LDS 48KB, regs ~150 -> 3 waves/SIMD (vs 2 before).
__global__ __launch_bounds__(256, 3) void kvproj_kernel(
    const float* __restrict__ WE, const unsigned short* __restrict__ Wkt,
    const unsigned short* __restrict__ Wvt, const float* __restrict__ bk,
    const float* __restrict__ bv, unsigned short* __restrict__ Kb,
    unsigned short* __restrict__ Vb) {
  __shared__ short Kbuf[3][128 * 32];  // 3 x 8192 B
  __shared__ short Vbuf[3][128 * 32];  // 3 x 8192 B

  int bx = blockIdx.x;
  int v0 = (bx >> 1) * 64;
  int colbase = (bx & 1) * 128;
  int t = threadIdx.x;
  int w = t >> 6, lane = t & 63, a = lane & 15, quad = lane >> 4;
  int wm = w >> 1, wn = w & 1;  // wave: row-half (32 rows) x col-half (64 cols)

  // stage K/V tile kt into buffer p: 4 global_load_lds per wave (2 K + 2 V)
  auto stageKV = [&](int kt, int p) {
#pragma unroll
    for (int i = 0; i < 2; ++i) {
      int s = w * 128 + i * 64 + lane;     // linear LDS 16B-chunk index
      int row = s >> 2;
      int cc = (s & 3) ^ ((row >> 1) & 3); // inverse-swizzled source chunk
      GLDS16(Wkt + (size_t)(colbase + row) * DW + kt * 32 + cc * 8,
             &Kbuf[p][(w * 128 + i * 64) * 8]);
      GLDS16(Wvt + (size_t)(colbase + row) * DW + kt * 32 + cc * 8,
             &Vbuf[p][(w * 128 + i * 64) * 8]);
    }
  };

  // hoisted WE row pointers for direct A-frag loads (clamped for pad rows;
  // pad results masked at store)
  const float* werow[2];
#pragma unroll
  for (int mb = 0; mb < 2; ++mb) {
    int grow = v0 + wm * 32 + mb * 16 + a;
    if (grow > VV - 1) grow = VV - 1;
    werow[mb] = WE + (size_t)grow * DW + quad * 8;
  }

  f32x4 Ck[2][4], Cv[2][4];
#pragma unroll
  for (int mb = 0; mb < 2; ++mb)
#pragma unroll
    for (int nb = 0; nb < 4; ++nb) {
      Ck[mb][nb] = (f32x4){0.f, 0.f, 0.f, 0.f};
      Cv[mb][nb] = (f32x4){0.f, 0.f, 0.f, 0.f};
    }

  stageKV(0, 0);
  stageKV(1, 1);

  int p = 0;
  for (int kt = 0; kt < 24; ++kt) {
    // wait ONLY the oldest stage (kt); stage kt+1 stays in flight
    if (kt < 23) {
      WAIT_VM(4);
    } else {
      WAIT_VM(0);
    }
    SBARRIER;

    // WE A-frag loads FIRST (older than restage in vmcnt FIFO)
    f32x4 lo0 = *(const f32x4*)(werow[0] + kt * 32);
    f32x4 hi0 = *(const f32x4*)(werow[0] + kt * 32 + 4);
    f32x4 lo1 = *(const f32x4*)(werow[1] + kt * 32);
    f32x4 hi1 = *(const f32x4*)(werow[1] + kt * 32 + 4);
    __builtin_amdgcn_sched_barrier(0);  // pin: A-loads issue before restage

    // restage into the buffer consumed at step kt-1: (kt+2)%3
    {
      int q = p - 1;
      if (q < 0) q = 2;
      if (kt < 22) stageKV(kt + 2, q);
    }

    // in-reg bf16 convert of A-frags
    sh8 A[2];
    {
      sh4 l4 = {(short)bfbits(lo0[0]), (short)bfbits(lo0[1]),
                (short)bfbits(lo0[2]), (short)bfbits(lo0[3])};
      sh4 h4 = {(short)bfbits(hi0[0]), (short)bfbits(hi0[1]),
                (short)bfbits(hi0[2]), (short)bfbits(hi0[3])};
      A[0] = __builtin_shufflevector(l4, h4, 0, 1, 2, 3, 4, 5, 6, 7);
      sh4 l5 = {(short)bfbits(lo1[0]), (short)bfbits(lo1[1]),
                (short)bfbits(lo1[2]), (short)bfbits(lo1[3])};
      sh4 h5 = {(short)bfbits(hi1[0]), (short)bfbits(hi1[1]),
                (short)bfbits(hi1[2]), (short)bfbits(hi1[3])};
      A[1] = __builtin_shufflevector(l5, h5, 0, 1, 2, 3, 4, 5, 6, 7);
    }

    // K/V B-frags from LDS (swizzled chunk -> ~2-way banks, free)
    sh8 Bk[4], Bv[4];
#pragma unroll
    for (int nb = 0; nb < 4; ++nb) {
      int krow = wn * 64 + nb * 16 + a;
      int cp = (quad ^ ((krow >> 1) & 3)) * 8;
      Bk[nb] = *(const sh8*)&Kbuf[p][krow * 32 + cp];
      Bv[nb] = *(const sh8*)&Vbuf[p][krow * 32 + cp];
    }
#pragma unroll
    for (int mb = 0; mb < 2; ++mb)
#pragma unroll
      for (int nb = 0; nb < 4; ++nb) {
        Ck[mb][nb] = __builtin_amdgcn_mfma_f32_16x16x32_bf16(
            A[mb], Bk[nb], Ck[mb][nb], 0, 0, 0);
        Cv[mb][nb] = __builtin_amdgcn_mfma_f32_16x16x32_bf16(
            A[mb], Bv[nb], Cv[mb][nb], 0, 0, 0);
      }

    p = (p == 2) ? 0 : p + 1;
  }

  // epilogue: bias + store bf16; pad rows -> 0
  float bkv[4], bvv[4];
#pragma unroll
  for (int nb = 0; nb < 4; ++nb) {
    int n = colbase + wn * 64 + nb * 16 + a;
    bkv[nb] = bk[n];
    bvv[nb] = bv[n];
  }
#pragma unroll
  for (int mb = 0; mb < 2; ++mb)
#pragma unroll
    for (int nb = 0; nb < 4; ++nb)
#pragma unroll
      for (int r = 0; r < 4; ++r) {
        int m = v0 + wm * 32 + mb * 16 + quad * 4 + r;
        int n = colbase + wn * 64 + nb * 16 + a;
        bool ok = m < VV;
        Kb[(size_t)m * DM + n] = ok ? bfbits(Ck[mb][nb][r] + bkv[nb]) : 0;
        Vb[(size_t)m * DM + n] = ok ? bfbits(Cv[mb][nb][r] + bvv[nb]) : 0;
      }
}

// ---------------- MFMA attention over the vocab axis ------------------------
// Raw barriers + lgkmcnt-only waits: the next-tile K/V register prefetch
// (issued right after the score MFMAs) stays in flight across both barriers.
// Q pre-scaled by log2(e): softmax uses exp2 directly, no max subtraction
// (shift-invariant, scores O(1)). Per-chunk partial stores when nc>1.
#define PST 72  // row stride (bf16) for Pb/Vt: 144 B = 16 B aligned
__global__ __launch_bounds__(256) void attn_kernel(
    const unsigned short* __restrict__ Qb, const unsigned short* __restrict__ Kb,
    const unsigned short* __restrict__ Vb, float* __restrict__ part, int bpb,
    int nc) {
  __shared__ short Pb[LL * PST];  // 18432 B
  __shared__ short Vt[EE * PST];  //  4608 B

  int bh = blockIdx.x / bpb;
  int chunk = blockIdx.x - bh * bpb;
  int b = bh >> 3, h = bh & 7;
  int t = threadIdx.x;
  int w = t >> 6;         // wave 0..3
  int lane = t & 63;
  int a = lane & 15;      // MFMA n / m lane coord
  int quad = lane >> 4;   // 0..3
  int vr = t >> 2, e0 = (t & 3) * 8;  // V staging identity

  // hoist Q B-frags: frag[tau] holds Q rows l=tau*16+a, e=quad*8+j (16B each)
  sh8 qf[8];
  const unsigned short* qbase = Qb + (size_t)(b * LL) * DM + h * EE;
#pragma unroll
  for (int tau = 0; tau < 8; ++tau)
    qf[tau] = *(const sh8*)(qbase + (size_t)(tau * 16 + a) * DM + quad * 8);

  f32x4 C[2][2];  // accum: l = 32w + mb*16 + quad*4 + r, e = nb*16 + a
#pragma unroll
  for (int mb = 0; mb < 2; ++mb)
#pragma unroll
    for (int nb = 0; nb < 2; ++nb)
      C[mb][nb] = (f32x4){0.f, 0.f, 0.f, 0.f};

  const int ntiles = VPAD >> 6;  // 786

  // prefetch first tile
  sh8 af, vv;
  {
    int v0 = chunk << 6;
    af = *(const sh8*)(Kb + (size_t)(v0 + 16 * w + a) * DM + h * EE + quad * 8);
    vv = *(const sh8*)(Vb + (size_t)(v0 + vr) * DM + h * EE + e0);
  }

  for (int tile = chunk; tile < ntiles; tile += bpb) {
    // scores: 8 MFMAs on prefetched af
    f32x4 S[8];
#pragma unroll
    for (int tau = 0; tau < 8; ++tau) {
      f32x4 z = {0.f, 0.f, 0.f, 0.f};
      S[tau] = __builtin_amdgcn_mfma_f32_16x16x32_bf16(af, qf[tau], z, 0, 0, 0);
    }

    // issue next tile's K-frag + V-rows NOW (af dead; vv still live -> vv2)
    sh8 af2 = af, vv2 = vv;
    int nt = tile + bpb;
    if (nt < ntiles) {
      int v0n = nt << 6;
      af2 = *(const sh8*)(Kb + (size_t)(v0n + 16 * w + a) * DM + h * EE + quad * 8);
      vv2 = *(const sh8*)(Vb + (size_t)(v0n + vr) * DM + h * EE + e0);
    }

    // register softmax over l per v-row r (no max-sub; shfl-sum over 16 lanes)
    float sm[4], inv[4];
#pragma unroll
    for (int r = 0; r < 4; ++r) sm[r] = 0.f;
#pragma unroll
    for (int tau = 0; tau < 8; ++tau)
#pragma unroll
      for (int r = 0; r < 4; ++r) {
        float ex = __builtin_amdgcn_exp2f(S[tau][r]);  // Q pre-scaled by log2e
        S[tau][r] = ex;
        sm[r] += ex;
      }
#pragma unroll
    for (int msk = 1; msk <= 8; msk <<= 1)
#pragma unroll
      for (int r = 0; r < 4; ++r)
        sm[r] += __shfl_xor(sm[r], msk);
#pragma unroll
    for (int r = 0; r < 4; ++r) inv[r] = 1.f / sm[r];

    // prev phase2 frag reads done before overwriting Pb/Vt (lgkm only --
    // the af2/vv2 prefetch stays in flight)
    WAIT_LGKM0;
    SBARRIER;

    // stage V^T: Vt[e][v_local]
    {
      const short* vs = (const short*)&vv;
#pragma unroll
      for (int j = 0; j < 8; ++j)
        Vt[(e0 + j) * PST + vr] = vs[j];
    }
    // write P^T bf16: Pb[l = tau*16+a][v_local = 16w + quad*4 + r]
#pragma unroll
    for (int tau = 0; tau < 8; ++tau) {
      ushort4 pk;
      pk.x = bfbits(S[tau][0] * inv[0]);
      pk.y = bfbits(S[tau][1] * inv[1]);
      pk.z = bfbits(S[tau][2] * inv[2]);
      pk.w = bfbits(S[tau][3] * inv[3]);
      *(ushort4*)&Pb[(tau * 16 + a) * PST + 16 * w + quad * 4] = pk;
    }
    WAIT_LGKM0;
    SBARRIER;

    af = af2;
    vv = vv2;

    // phase 2: C[l][e] += P^T[l][v] · V[v][e]
    sh8 Afr[2][2], Bfr[2][2];
#pragma unroll
    for (int mb = 0; mb < 2; ++mb)
#pragma unroll
      for (int kb = 0; kb < 2; ++kb)
        Afr[mb][kb] =
            *(const sh8*)&Pb[(32 * w + mb * 16 + a) * PST + kb * 32 + quad * 8];
#pragma unroll
    for (int kb = 0; kb < 2; ++kb)
#pragma unroll
      for (int nb = 0; nb < 2; ++nb)
        Bfr[kb][nb] = *(const sh8*)&Vt[(nb * 16 + a) * PST + kb * 32 + quad * 8];
#pragma unroll
    for (int kb = 0; kb < 2; ++kb)
#pragma unroll
      for (int mb = 0; mb < 2; ++mb)
#pragma unroll
        for (int nb = 0; nb < 2; ++nb)
          C[mb][nb] = __builtin_amdgcn_mfma_f32_16x16x32_bf16(
              Afr[mb][kb], Bfr[kb][nb], C[mb][nb], 0, 0, 0);
  }

  // epilogue: partial store (nc>1) or atomicAdd fallback (nc==1)
#pragma unroll
  for (int mb = 0; mb < 2; ++mb)
#pragma unroll
    for (int nb = 0; nb < 2; ++nb)
#pragma unroll
      for (int r = 0; r < 4; ++r) {
        int l = 32 * w + mb * 16 + quad * 4 + r;
        int e = nb * 16 + a;
        size_t idx = (size_t)(b * LL + l) * DM + h * EE + e;
        if (nc > 1)
          part[(size_t)chunk * (BB * LL * DM) + idx] = C[mb][nb][r];
        else
          atomicAdd(&part[idx], C[mb][nb][r]);
      }
}

// -------- output projection: (sum_c part[c]) @ Wo + bo -> fp32 out ----------
__global__ __launch_bounds__(256) void outproj_kernel(
    const float* __restrict__ part, const float* __restrict__ Wo,
    const float* __restrict__ bo, float* __restrict__ out, int nc) {
  __shared__ float row[DM];
  int r = blockIdx.x, n = threadIdx.x;
  float s = 0.f;
  for (int c = 0; c < nc; ++c)
    s += part[(size_t)c * (BB * LL * DM) + (size_t)r * DM + n];
  row[n] = s;
  __syncthreads();
  float acc = bo[n];
#pragma unroll 8
  for (int k = 0; k < DM; ++k)
    acc = fmaf(row[k], Wo[k * DM + n], acc);
  out[r * DM + n] = acc;
}

extern "C" void kernel_launch(void* const* d_in, const int* in_sizes, int n_in,
                              void* d_out, int out_size, void* d_ws, size_t ws_size,
                              hipStream_t stream) {
  const float* tse = (const float*)d_in[0];
  const float* WE  = (const float*)d_in[1];
  const float* Wq  = (const float*)d_in[2];
  const float* bq  = (const float*)d_in[3];
  const float* Wk  = (const float*)d_in[4];
  const float* bk  = (const float*)d_in[5];
  const float* Wv  = (const float*)d_in[6];
  const float* bv  = (const float*)d_in[7];
  const float* Wo  = (const float*)d_in[8];
  const float* bo  = (const float*)d_in[9];
  float* out = (float*)d_out;

  // ws: Qb | Kb | Vb | X.  X holds Wkt+Wvt during prep->kvproj, then is
  // reused for the attn partials (lifetimes disjoint).
  char* ws = (char*)d_ws;
  const size_t QB_BYTES   = (size_t)BB * LL * DM * 2;    // 262144
  const size_t KV_BYTES   = (size_t)VPAD * DM * 2;       // 25755648
  const size_t WT_BYTES   = (size_t)DM * DW * 2;         // 393216
  const size_t PART_BYTES = (size_t)BB * LL * DM * 4;    // 524288
  unsigned short* Qb  = (unsigned short*)ws;
  unsigned short* Kb  = (unsigned short*)(ws + QB_BYTES);
  unsigned short* Vb  = (unsigned short*)(ws + QB_BYTES + KV_BYTES);
  char* X = ws + QB_BYTES + 2 * KV_BYTES;
  unsigned short* Wkt = (unsigned short*)X;
  unsigned short* Wvt = (unsigned short*)(X + WT_BYTES);
  float* part = (float*)X;  // aliases Wkt/Wvt AFTER kvproj is done

  const int BPB = 32;  // v-chunks per (b,h): grid = 32*32 = 1024 blocks

  // partials mode needs X to hold BPB slices of 512KB
  const size_t NEED_PART =
      QB_BYTES + 2 * KV_BYTES + (size_t)BPB * PART_BYTES;  // ~68.6 MB
  const int nc = (ws_size >= NEED_PART) ? BPB : 1;

  prep_kernel<<<96 + BB * LL, 256, 0, stream>>>(Wk, Wv, Wkt, Wvt, tse, Wq, bq, Qb);
  kvproj_kernel<<<(VPAD / 64) * 2, 256, 0, stream>>>(WE, Wkt, Wvt, bk, bv, Kb, Vb);
  if (nc == 1)
    (void)hipMemsetAsync(part, 0, PART_BYTES, stream);
  attn_kernel<<<32 * BPB, 256, 0, stream>>>(Qb, Kb, Vb, part, BPB, nc);
  outproj_kernel<<<BB * LL, 256, 0, stream>>>(part, Wo, bo, out, nc);
}

// Round 7
// 408.714 us; speedup vs baseline: 1.1281x; 1.1281x over previous
//
#include <hip/hip_runtime.h>
#include <hip/hip_bf16.h>
#include <string.h>

#define BB 4
#define LL 128
#define DM 256
#define VV 50257
#define VPAD 50304   // 786 tiles * 64; also 393 * 128
#define DW 768
#define HH 8
#define EE 32

typedef __attribute__((ext_vector_type(8))) short sh8;    // 8 bf16 = 4 VGPR
typedef __attribute__((ext_vector_type(4))) short sh4;    // 4 bf16 = 2 VGPR
typedef __attribute__((ext_vector_type(4))) float f32x4;  // MFMA accum

static __device__ inline unsigned short bfbits(float x) {
  __hip_bfloat16 h = __float2bfloat16(x);
  unsigned short u;
  __builtin_memcpy(&u, &h, 2);
  return u;
}

// global -> LDS direct 16B copy (per-lane global src, wave-uniform LDS base;
// HW adds lane*16 to the LDS destination)
#define GLDS16(gsrc, ldst)                                                    \
  __builtin_amdgcn_global_load_lds(                                          \
      (const __attribute__((address_space(1))) void*)(gsrc),                 \
      (__attribute__((address_space(3))) void*)(ldst), 16, 0, 0)

#define WAIT_VM(N)                                                           \
  __builtin_amdgcn_sched_barrier(0);                                         \
  asm volatile("s_waitcnt vmcnt(" #N ")" ::: "memory");                      \
  __builtin_amdgcn_sched_barrier(0)
#define WAIT_LGKM0                                                           \
  asm volatile("s_waitcnt lgkmcnt(0)" ::: "memory");                         \
  __builtin_amdgcn_sched_barrier(0)
#define SBARRIER                                                             \
  __builtin_amdgcn_sched_barrier(0);                                         \
  __builtin_amdgcn_s_barrier();                                              \
  __builtin_amdgcn_sched_barrier(0)

// 16x16x16 bf16 MFMA (K=16): B-frag layout [k=quad*4+j][col=lane&15] matches
// the 16x16x32 C/D layout [row=quad*4+r][col=lane&15] -- the basis of the
// shuffle-free attention phase 2.
#if __has_builtin(__builtin_amdgcn_mfma_f32_16x16x16bf16_1k)
#define MFMA16(A, B, C) __builtin_amdgcn_mfma_f32_16x16x16bf16_1k(A, B, C, 0, 0, 0)
#elif __has_builtin(__builtin_amdgcn_mfma_f32_16x16x16_bf16)
#define MFMA16(A, B, C) __builtin_amdgcn_mfma_f32_16x16x16_bf16(A, B, C, 0, 0, 0)
#else
static __device__ inline f32x4 mfma16_asm(sh4 a, sh4 b, f32x4 c) {
  asm volatile("v_mfma_f32_16x16x16_bf16 %0, %1, %2, %0"
               : "+v"(c) : "v"(a), "v"(b));
  return c;
}
#define MFMA16(A, B, C) mfma16_asm(A, B, C)
#endif

// ------------- prep: wtrans (blocks 0..95) + qproj (blocks 96..607) ---------
__global__ __launch_bounds__(256) void prep_kernel(
    const float* __restrict__ Wk, const float* __restrict__ Wv,
    unsigned short* __restrict__ Wkt, unsigned short* __restrict__ Wvt,
    const float* __restrict__ tse, const float* __restrict__ Wq,
    const float* __restrict__ bq, unsigned short* __restrict__ Qb) {
  __shared__ float tileS[64][65];
  int bid = blockIdx.x;
  int t = threadIdx.x;
  if (bid < 96) {
    int z = bid / 48, rem = bid - z * 48;
    int x = rem % 12, y = rem / 12;
    const float* src = z ? Wv : Wk;
    unsigned short* dst = z ? Wvt : Wkt;
    int k0 = x * 64, n0 = y * 64;
    int c = t & 63, rb = t >> 6;
#pragma unroll
    for (int j = 0; j < 16; ++j) {
      int r = j * 4 + rb;
      tileS[r][c] = src[(size_t)(k0 + r) * DM + n0 + c];
    }
    __syncthreads();
#pragma unroll
    for (int j = 0; j < 16; ++j) {
      int r = j * 4 + rb;
      dst[(size_t)(n0 + r) * DW + k0 + c] = bfbits(tileS[c][r]);
    }
  } else {
    int r = bid - 96;  // 0..511
    int n = t;         // 0..255
    float* row = &tileS[0][0];
    row[n] = tse[r * DM + n];
    __syncthreads();
    float acc = bq[n];
#pragma unroll 8
    for (int k = 0; k < DM; ++k)
      acc = fmaf(row[k], Wq[k * DM + n], acc);
    const float scale = 0.17677669529663687f * 1.4426950408889634f;  // 1/sqrt(32)*log2e
    Qb[r * DM + n] = bfbits(acc * scale);
  }
}

// ------------- K,V projection via MFMA: [VPAD,768]@[768,256] x2 -------------
// R4-measured structure (112 us) restored verbatim: 128x128 tile, WE staged
// fp32 via global_load_lds (2-step latency cover), depth-2 counted vmcnt,
// raw barriers. Diffs vs R4: (1) K/V chunk swizzle c^((row>>1)&3) (R6-proven,
// conflicts->0); (2) V stored TRANSPOSED (Vbt [DM][VPAD]) for the LDS-free
// attention phase 2.
__global__ __launch_bounds__(256, 2) void kvproj_kernel(
    const float* __restrict__ WE, const unsigned short* __restrict__ Wkt,
    const unsigned short* __restrict__ Wvt, const float* __restrict__ bk,
    const float* __restrict__ bv, unsigned short* __restrict__ Kb,
    unsigned short* __restrict__ Vbt) {
  __shared__ float WEf[2][128 * 32];   // 2 x 16384 B
  __shared__ short Kbuf[2][128 * 32];  // 2 x  8192 B
  __shared__ short Vbuf[2][128 * 32];  // 2 x  8192 B

  int bx = blockIdx.x;
  int v0 = (bx >> 1) * 128;
  int colbase = (bx & 1) * 128;
  int t = threadIdx.x;
  int w = t >> 6, lane = t & 63, a = lane & 15, quad = lane >> 4;
  int wm = w >> 1, wn = w & 1;

  // stage tile kt into buffer p: 8 global_load_lds per wave (4 WE + 2 K + 2 V)
  auto stage = [&](int kt, int p) {
#pragma unroll
    for (int i = 0; i < 4; ++i) {
      int s = w * 256 + i * 64 + lane;       // linear LDS 16B-chunk index
      int row = s >> 3;
      int cc = (s & 7) ^ (row & 7);          // inverse-swizzled source chunk
      int grow = v0 + row;
      if (grow > VV - 1) grow = VV - 1;      // clamp (pad rows masked at store)
      GLDS16(WE + (size_t)grow * DW + kt * 32 + cc * 4,
             &WEf[p][(w * 256 + i * 64) * 4]);
    }
#pragma unroll
    for (int i = 0; i < 2; ++i) {
      int s = w * 128 + i * 64 + lane;
      int row = s >> 2;
      int cc = (s & 3) ^ ((row >> 1) & 3);   // inverse-swizzled source chunk
      GLDS16(Wkt + (size_t)(colbase + row) * DW + kt * 32 + cc * 8,
             &Kbuf[p][(w * 128 + i * 64) * 8]);
      GLDS16(Wvt + (size_t)(colbase + row) * DW + kt * 32 + cc * 8,
             &Vbuf[p][(w * 128 + i * 64) * 8]);
    }
  };

  f32x4 Ck[4][4], Cv[4][4];
#pragma unroll
  for (int mb = 0; mb < 4; ++mb)
#pragma unroll
    for (int nb = 0; nb < 4; ++nb) {
      Ck[mb][nb] = (f32x4){0.f, 0.f, 0.f, 0.f};
      Cv[mb][nb] = (f32x4){0.f, 0.f, 0.f, 0.f};
    }

  stage(0, 0);
  stage(1, 1);

  for (int kt = 0; kt < 24; ++kt) {
    int p = kt & 1;
    // wait ONLY the oldest stage (kt); stage kt+1 stays in flight
    if (kt < 23) {
      WAIT_VM(8);
    } else {
      WAIT_VM(0);
    }
    SBARRIER;

    // fragment reads from buf[p]
    sh8 A[4], Bk[4], Bv[4];
#pragma unroll
    for (int mb = 0; mb < 4; ++mb) {
      int row = wm * 64 + mb * 16 + a;
      const float* rp = &WEf[p][row * 32];
      f32x4 lo = *(const f32x4*)(rp + ((2 * quad) ^ (a & 7)) * 4);
      f32x4 hi = *(const f32x4*)(rp + ((2 * quad + 1) ^ (a & 7)) * 4);
      sh4 l4 = {(short)bfbits(lo[0]), (short)bfbits(lo[1]),
                (short)bfbits(lo[2]), (short)bfbits(lo[3])};
      sh4 h4 = {(short)bfbits(hi[0]), (short)bfbits(hi[1]),
                (short)bfbits(hi[2]), (short)bfbits(hi[3])};
      A[mb] = __builtin_shufflevector(l4, h4, 0, 1, 2, 3, 4, 5, 6, 7);
    }
#pragma unroll
    for (int nb = 0; nb < 4; ++nb) {
      int krow = (wn * 4 + nb) * 16 + a;
      int cp = (quad ^ ((krow >> 1) & 3)) * 8;
      Bk[nb] = *(const sh8*)&Kbuf[p][krow * 32 + cp];
      Bv[nb] = *(const sh8*)&Vbuf[p][krow * 32 + cp];
    }
#pragma unroll
    for (int mb = 0; mb < 4; ++mb)
#pragma unroll
      for (int nb = 0; nb < 4; ++nb) {
        Ck[mb][nb] = __builtin_amdgcn_mfma_f32_16x16x32_bf16(
            A[mb], Bk[nb], Ck[mb][nb], 0, 0, 0);
        Cv[mb][nb] = __builtin_amdgcn_mfma_f32_16x16x32_bf16(
            A[mb], Bv[nb], Cv[mb][nb], 0, 0, 0);
      }

    // all waves done reading buf[p] before restaging into it
    WAIT_LGKM0;
    SBARRIER;
    if (kt < 22) stage(kt + 2, p);
  }

  // epilogue: bias + store; K row-major bf16, V TRANSPOSED (Vbt[n][v]).
  float bkv[4], bvv[4];
#pragma unroll
  for (int nb = 0; nb < 4; ++nb) {
    int n = colbase + (wn * 4 + nb) * 16 + a;
    bkv[nb] = bk[n];
    bvv[nb] = bv[n];
  }
#pragma unroll
  for (int mb = 0; mb < 4; ++mb)
#pragma unroll
    for (int nb = 0; nb < 4; ++nb) {
      int m0 = v0 + wm * 64 + mb * 16 + quad * 4;
      int n = colbase + (wn * 4 + nb) * 16 + a;
      sh4 vq;
#pragma unroll
      for (int r = 0; r < 4; ++r) {
        int m = m0 + r;
        bool ok = m < VV;
        Kb[(size_t)m * DM + n] = ok ? bfbits(Ck[mb][nb][r] + bkv[nb]) : 0;
        vq[r] = ok ? (short)bfbits(Cv[mb][nb][r] + bvv[nb]) : (short)0;
      }
      *(sh4*)&Vbt[(size_t)n * VPAD + m0] = vq;  // 8B store, pad cols zeroed
    }
}

// ---------------- MFMA attention: barrier-free, LDS-free main loop ----------
// Phase 1 (mfma16x16x32, A=K-frag, B=Q-frag) leaves S[tau][r] =
// P^T[v=quad*4+r][l=tau*16+a] -- EXACTLY the B-frag layout of
// mfma_f32_16x16x16_bf16 (k=quad*4+j, col=lane&15). So each wave contracts
// its own 16 v-rows in phase 2 with zero cross-lane data movement:
//   C2[nb][tau] += V^T-frag[nb] * P-frag[tau],  A-frag read 8B from Vbt.
// No barriers, no LDS in the loop; waves fully independent. One LDS
// reduction across the 4 waves at block end (stride-129: conflict-free for
// both the write pattern and the e-fast read pattern).
// Q pre-scaled by log2(e): exp2 softmax, no max-sub (shift-invariant).
__global__ __launch_bounds__(256) void attn_kernel(
    const unsigned short* __restrict__ Qb, const unsigned short* __restrict__ Kb,
    const unsigned short* __restrict__ Vbt, float* __restrict__ part, int bpb,
    int nc) {
  __shared__ float Cred[4][32][129];  // 66048 B, epilogue only

  int bh = blockIdx.x / bpb;
  int chunk = blockIdx.x - bh * bpb;
  int b = bh >> 3, h = bh & 7;
  int t = threadIdx.x;
  int w = t >> 6;         // wave 0..3 (owns v-rows 16w..16w+15 of each tile)
  int lane = t & 63;
  int a = lane & 15;      // MFMA col lane coord
  int quad = lane >> 4;   // 0..3

  // hoist Q B-frags: frag[tau] holds Q rows l=tau*16+a, e=quad*8+j (16B each)
  sh8 qf[8];
  const unsigned short* qbase = Qb + (size_t)(b * LL) * DM + h * EE;
#pragma unroll
  for (int tau = 0; tau < 8; ++tau)
    qf[tau] = *(const sh8*)(qbase + (size_t)(tau * 16 + a) * DM + quad * 8);

  // phase-2 accumulators: e = nb*16 + quad*4 + r, l = tau*16 + a
  f32x4 C2[2][8];
#pragma unroll
  for (int nb = 0; nb < 2; ++nb)
#pragma unroll
    for (int tau = 0; tau < 8; ++tau)
      C2[nb][tau] = (f32x4){0.f, 0.f, 0.f, 0.f};

  const int ntiles = VPAD >> 6;  // 786

  // prefetch first tile: K-frag (16B) + V^T A-frags (2 x 8B)
  sh8 af;
  sh4 av[2];
  {
    int v0 = chunk << 6;
    af = *(const sh8*)(Kb + (size_t)(v0 + 16 * w + a) * DM + h * EE + quad * 8);
#pragma unroll
    for (int nb = 0; nb < 2; ++nb)
      av[nb] = *(const sh4*)(Vbt + (size_t)(h * EE + nb * 16 + a) * VPAD +
                             v0 + 16 * w + quad * 4);
  }

  for (int tile = chunk; tile < ntiles; tile += bpb) {
    // phase 1: S[tau] = K-rows x Q  (S[tau][r] = P^T[v=quad*4+r][l=tau*16+a])
    f32x4 S[8];
#pragma unroll
    for (int tau = 0; tau < 8; ++tau) {
      f32x4 z = {0.f, 0.f, 0.f, 0.f};
      S[tau] = __builtin_amdgcn_mfma_f32_16x16x32_bf16(af, qf[tau], z, 0, 0, 0);
    }

    // prefetch next tile (full-tile latency cover; no barriers interfere)
    sh8 af2 = af;
    sh4 av2[2] = {av[0], av[1]};
    int nt = tile + bpb;
    if (nt < ntiles) {
      int v0n = nt << 6;
      af2 = *(const sh8*)(Kb + (size_t)(v0n + 16 * w + a) * DM + h * EE + quad * 8);
#pragma unroll
      for (int nb = 0; nb < 2; ++nb)
        av2[nb] = *(const sh4*)(Vbt + (size_t)(h * EE + nb * 16 + a) * VPAD +
                                v0n + 16 * w + quad * 4);
    }

    // softmax over l per v-row r: exp2 (Q pre-scaled), shfl-sum over 16 lanes
    float sm[4], inv[4];
#pragma unroll
    for (int r = 0; r < 4; ++r) sm[r] = 0.f;
#pragma unroll
    for (int tau = 0; tau < 8; ++tau)
#pragma unroll
      for (int r = 0; r < 4; ++r) {
        float ex = __builtin_amdgcn_exp2f(S[tau][r]);
        S[tau][r] = ex;
        sm[r] += ex;
      }
#pragma unroll
    for (int msk = 1; msk <= 8; msk <<= 1)
#pragma unroll
      for (int r = 0; r < 4; ++r)
        sm[r] += __shfl_xor(sm[r], msk);
#pragma unroll
    for (int r = 0; r < 4; ++r) inv[r] = 1.f / sm[r];

    // pack P-frags in-register (B-frag of 16x16x16: k=quad*4+r, col=a)
    sh4 pb[8];
#pragma unroll
    for (int tau = 0; tau < 8; ++tau) {
      pb[tau][0] = (short)bfbits(S[tau][0] * inv[0]);
      pb[tau][1] = (short)bfbits(S[tau][1] * inv[1]);
      pb[tau][2] = (short)bfbits(S[tau][2] * inv[2]);
      pb[tau][3] = (short)bfbits(S[tau][3] * inv[3]);
    }

    // phase 2: C2[e][l] += V^T x P  over this wave's 16 v-rows (k=16)
#pragma unroll
    for (int nb = 0; nb < 2; ++nb)
#pragma unroll
      for (int tau = 0; tau < 8; ++tau)
        C2[nb][tau] = MFMA16(av[nb], pb[tau], C2[nb][tau]);

    af = af2;
    av[0] = av2[0];
    av[1] = av2[1];
  }

  // epilogue: reduce the 4 waves' partials in LDS, then store (nc>1) or
  // atomicAdd (nc==1). Cred[w][e][l], stride 129.
#pragma unroll
  for (int nb = 0; nb < 2; ++nb)
#pragma unroll
    for (int tau = 0; tau < 8; ++tau)
#pragma unroll
      for (int r = 0; r < 4; ++r)
        Cred[w][nb * 16 + quad * 4 + r][tau * 16 + a] = C2[nb][tau][r];
  __syncthreads();
#pragma unroll
  for (int j = 0; j < 16; ++j) {
    int f = t + 256 * j;          // 0..4095, e-fast
    int e = f & 31, l = f >> 5;
    float s = Cred[0][e][l] + Cred[1][e][l] + Cred[2][e][l] + Cred[3][e][l];
    size_t idx = (size_t)(b * LL + l) * DM + h * EE + e;
    if (nc > 1)
      part[(size_t)chunk * (BB * LL * DM) + idx] = s;
    else
      atomicAdd(&part[idx], s);
  }
}

// -------- output projection: (sum_c part[c]) @ Wo + bo -> fp32 out ----------
__global__ __launch_bounds__(256) void outproj_kernel(
    const float* __restrict__ part, const float* __restrict__ Wo,
    const float* __restrict__ bo, float* __restrict__ out, int nc) {
  __shared__ float row[DM];
  int r = blockIdx.x, n = threadIdx.x;
  float s = 0.f;
  for (int c = 0; c < nc; ++c)
    s += part[(size_t)c * (BB * LL * DM) + (size_t)r * DM + n];
  row[n] = s;
  __syncthreads();
  float acc = bo[n];
#pragma unroll 8
  for (int k = 0; k < DM; ++k)
    acc = fmaf(row[k], Wo[k * DM + n], acc);
  out[r * DM + n] = acc;
}

extern "C" void kernel_launch(void* const* d_in, const int* in_sizes, int n_in,
                              void* d_out, int out_size, void* d_ws, size_t ws_size,
                              hipStream_t stream) {
  const float* tse = (const float*)d_in[0];
  const float* WE  = (const float*)d_in[1];
  const float* Wq  = (const float*)d_in[2];
  const float* bq  = (const float*)d_in[3];
  const float* Wk  = (const float*)d_in[4];
  const float* bk  = (const float*)d_in[5];
  const float* Wv  = (const float*)d_in[6];
  const float* bv  = (const float*)d_in[7];
  const float* Wo  = (const float*)d_in[8];
  const float* bo  = (const float*)d_in[9];
  float* out = (float*)d_out;

  // ws: Qb | Kb | Vbt | X.  X holds Wkt+Wvt during prep->kvproj, then is
  // reused for the attn partials (lifetimes disjoint).
  char* ws = (char*)d_ws;
  const size_t QB_BYTES   = (size_t)BB * LL * DM * 2;    // 262144
  const size_t KV_BYTES   = (size_t)VPAD * DM * 2;       // 25755648
  const size_t WT_BYTES   = (size_t)DM * DW * 2;         // 393216
  const size_t PART_BYTES = (size_t)BB * LL * DM * 4;    // 524288
  unsigned short* Qb  = (unsigned short*)ws;
  unsigned short* Kb  = (unsigned short*)(ws + QB_BYTES);
  unsigned short* Vbt = (unsigned short*)(ws + QB_BYTES + KV_BYTES);
  char* X = ws + QB_BYTES + 2 * KV_BYTES;
  unsigned short* Wkt = (unsigned short*)X;
  unsigned short* Wvt = (unsigned short*)(X + WT_BYTES);
  float* part = (float*)X;  // aliases Wkt/Wvt AFTER kvproj is done

  const int BPB = 32;  // v-chunks per (b,h): grid = 32*32 = 1024 blocks

  // partials mode needs X to hold BPB slices of 512KB
  const size_t NEED_PART =
      QB_BYTES + 2 * KV_BYTES + (size_t)BPB * PART_BYTES;  // ~68.6 MB
  const int nc = (ws_size >= NEED_PART) ? BPB : 1;

  prep_kernel<<<96 + BB * LL, 256, 0, stream>>>(Wk, Wv, Wkt, Wvt, tse, Wq, bq, Qb);
  kvproj_kernel<<<(VPAD / 128) * 2, 256, 0, stream>>>(WE, Wkt, Wvt, bk, bv, Kb, Vbt);
  if (nc == 1)
    (void)hipMemsetAsync(part, 0, PART_BYTES, stream);
  attn_kernel<<<32 * BPB, 256, 0, stream>>>(Qb, Kb, Vbt, part, BPB, nc);
  outproj_kernel<<<BB * LL, 256, 0, stream>>>(part, Wo, bo, out, nc);
}